// Round 1
// baseline (955.713 us; speedup 1.0000x reference)
//
#include <hip/hip_runtime.h>

#define N_NODES 100000
#define N_EDGES 1200000
#define CH 64
#define NG 256
#define OC 8

// ---------------- degree count ----------------
__global__ void count_k(const int* __restrict__ dst, int* __restrict__ cnt) {
  int e = blockIdx.x * blockDim.x + threadIdx.x;
  if (e < N_EDGES) atomicAdd(&cnt[dst[e]], 1);
}

// ---------------- edge scatter: agg[dst] += x[src] ----------------
// one wave per edge iteration; lane = channel (coalesced 256B row read,
// 64 consecutive-address f32 atomics)
__global__ void scatter_k(const float* __restrict__ x, const int* __restrict__ src,
                          const int* __restrict__ dst, float* __restrict__ agg) {
  const int lane = threadIdx.x & 63;
  int wid = blockIdx.x * (blockDim.x >> 6) + (threadIdx.x >> 6);
  const int nw = gridDim.x * (blockDim.x >> 6);
  for (int e = wid; e < N_EDGES; e += nw) {
    int s = src[e], d = dst[e];
    atomicAdd(&agg[d * CH + lane], x[s * CH + lane]);
  }
}

// ---------------- per-node transform ----------------
// out[n][j] = relu( (agg[n]/max(cnt,1)) . Wl[j] + bl[j] + xr[n] . Wr[j] )
// Weights staged transposed in LDS (Wt[k][j] -> conflict-free lane reads).
// NOTE: xr and out may alias (layer-2 in-place) -> no __restrict__ on them.
__global__ __launch_bounds__(256) void combine_k(
    const float* __restrict__ agg, const int* __restrict__ cnt,
    const float* xr_, const float* __restrict__ Wl,
    const float* __restrict__ bl, const float* __restrict__ Wr,
    float* out) {
  __shared__ float Wlt[CH * CH];
  __shared__ float Wrt[CH * CH];
  for (int i = threadIdx.x; i < CH * CH; i += blockDim.x) {
    int j = i >> 6, k = i & 63;
    Wlt[k * CH + j] = Wl[i];
    Wrt[k * CH + j] = Wr[i];
  }
  __syncthreads();
  const int lane = threadIdx.x & 63;
  int wid = blockIdx.x * (blockDim.x >> 6) + (threadIdx.x >> 6);
  const int nw = gridDim.x * (blockDim.x >> 6);
  const float bias = bl[lane];
  for (int n = wid; n < N_NODES; n += nw) {
    float c = (float)cnt[n];
    float inv = c > 0.f ? 1.f / c : 1.f;
    float a = agg[n * CH + lane] * inv;
    float xv = xr_[n * CH + lane];
    float acc = bias;
#pragma unroll
    for (int k = 0; k < CH; ++k) {
      acc += __shfl(a, k) * Wlt[k * CH + lane];
      acc += __shfl(xv, k) * Wrt[k * CH + lane];
    }
    out[n * CH + lane] = fmaxf(acc, 0.f);
  }
}

// ---------------- pooled sum over sorted batch ----------------
// contiguous node chunk per wave; flush atomics only on graph-id change
__global__ void pool_k(const float* __restrict__ h, const int* __restrict__ batch,
                       float* __restrict__ gsum, int* __restrict__ gcnt) {
  const int lane = threadIdx.x & 63;
  int wid = blockIdx.x * (blockDim.x >> 6) + (threadIdx.x >> 6);
  const int nw = gridDim.x * (blockDim.x >> 6);
  int per = (N_NODES + nw - 1) / nw;
  int s = wid * per;
  int e = s + per;
  if (e > N_NODES) e = N_NODES;
  if (s >= e) return;
  int cur = batch[s];
  float acc = 0.f;
  int c = 0;
  for (int n = s; n < e; ++n) {
    int g = batch[n];
    if (g != cur) {
      atomicAdd(&gsum[cur * CH + lane], acc);
      if (lane == 0) atomicAdd(&gcnt[cur], c);
      cur = g; acc = 0.f; c = 0;
    }
    acc += h[n * CH + lane];
    c++;
  }
  atomicAdd(&gsum[cur * CH + lane], acc);
  if (lane == 0) atomicAdd(&gcnt[cur], c);
}

// ---------------- final projection: out[g][o] = (gsum[g]/cnt) . Wc[o] + bc[o] ----------------
__global__ void final_k(const float* __restrict__ gsum, const int* __restrict__ gcnt,
                        const float* __restrict__ Wc, const float* __restrict__ bc,
                        float* __restrict__ out) {
  __shared__ float Wcs[OC * CH];
  __shared__ float bcs[OC];
  for (int i = threadIdx.x; i < OC * CH; i += blockDim.x) Wcs[i] = Wc[i];
  if (threadIdx.x < OC) bcs[threadIdx.x] = bc[threadIdx.x];
  __syncthreads();
  int g = threadIdx.x;  // 256 threads = 256 graphs
  float c = (float)gcnt[g];
  float inv = c > 0.f ? 1.f / c : 1.f;
  float gr[CH];
#pragma unroll
  for (int k = 0; k < CH; ++k) gr[k] = gsum[g * CH + k] * inv;
#pragma unroll
  for (int o = 0; o < OC; ++o) {
    float acc = bcs[o];
#pragma unroll
    for (int k = 0; k < CH; ++k) acc += gr[k] * Wcs[o * CH + k];
    out[g * OC + o] = acc;
  }
}

extern "C" void kernel_launch(void* const* d_in, const int* in_sizes, int n_in,
                              void* d_out, int out_size, void* d_ws, size_t ws_size,
                              hipStream_t stream) {
  const float* x   = (const float*)d_in[0];
  const int*   ei  = (const int*)d_in[1];
  const int*   bat = (const int*)d_in[2];
  const float* W1l = (const float*)d_in[3];
  const float* b1l = (const float*)d_in[4];
  const float* W1r = (const float*)d_in[5];
  const float* W2l = (const float*)d_in[6];
  const float* b2l = (const float*)d_in[7];
  const float* W2r = (const float*)d_in[8];
  const float* Wc  = (const float*)d_in[9];
  const float* bc  = (const float*)d_in[10];
  float* out = (float*)d_out;

  char* ws = (char*)d_ws;
  const size_t AGG_OFF  = 0;                       // 25,600,000 B
  const size_t H1_OFF   = 25600000;                // 25,600,000 B
  const size_t CNT_OFF  = 51200000;                //    400,000 B
  const size_t GSUM_OFF = 51600000;                //     65,536 B
  const size_t GCNT_OFF = 51665536;                //      1,024 B
  float* agg  = (float*)(ws + AGG_OFF);
  float* h1   = (float*)(ws + H1_OFF);
  int*   cnt  = (int*)(ws + CNT_OFF);
  float* gsum = (float*)(ws + GSUM_OFF);
  int*   gcnt = (int*)(ws + GCNT_OFF);

  const int* src = ei;
  const int* dst = ei + N_EDGES;

  // zero accumulators (ws is poisoned 0xAA once; we re-zero every call)
  hipMemsetAsync(agg, 0, (size_t)N_NODES * CH * sizeof(float), stream);
  hipMemsetAsync(cnt, 0, (size_t)N_NODES * sizeof(int), stream);
  hipMemsetAsync(gsum, 0, (size_t)NG * CH * sizeof(float) + NG * sizeof(int), stream);

  count_k<<<(N_EDGES + 255) / 256, 256, 0, stream>>>(dst, cnt);

  // ---- layer 1 ----
  scatter_k<<<8192, 256, 0, stream>>>(x, src, dst, agg);
  combine_k<<<512, 256, 0, stream>>>(agg, cnt, x, W1l, b1l, W1r, h1);

  // ---- layer 2 (reuse agg; h2 written in place over h1) ----
  hipMemsetAsync(agg, 0, (size_t)N_NODES * CH * sizeof(float), stream);
  scatter_k<<<8192, 256, 0, stream>>>(h1, src, dst, agg);
  combine_k<<<512, 256, 0, stream>>>(agg, cnt, h1, W2l, b2l, W2r, h1);

  // ---- pool + classify ----
  pool_k<<<256, 256, 0, stream>>>(h1, bat, gsum, gcnt);
  final_k<<<1, 256, 0, stream>>>(gsum, gcnt, Wc, bc, out);
}

// Round 2
// 450.828 us; speedup vs baseline: 2.1199x; 2.1199x over previous
//
#include <hip/hip_runtime.h>

#define N_NODES 100000
#define N_EDGES 1200000
#define CH 64
#define NG 256
#define OC 8
#define NB 391  // ceil(N_NODES/256)

__device__ __forceinline__ float bcast(float v, int k) {
  return __int_as_float(__builtin_amdgcn_readlane(__float_as_int(v), k));
}

// ---------------- degree count ----------------
__global__ void count_k(const int* __restrict__ dst, int* __restrict__ cnt) {
  int e = blockIdx.x * blockDim.x + threadIdx.x;
  if (e < N_EDGES) atomicAdd(&cnt[dst[e]], 1);
}

// ---------------- 3-kernel exclusive scan: cnt -> rowptr ----------------
__global__ void scan1_k(const int* __restrict__ cnt, int* __restrict__ rp,
                        int* __restrict__ bsum) {
  __shared__ int s[256];
  int i = blockIdx.x * 256 + threadIdx.x;
  int v = (i < N_NODES) ? cnt[i] : 0;
  s[threadIdx.x] = v;
  __syncthreads();
  for (int o = 1; o < 256; o <<= 1) {
    int t = (threadIdx.x >= o) ? s[threadIdx.x - o] : 0;
    __syncthreads();
    s[threadIdx.x] += t;
    __syncthreads();
  }
  if (i < N_NODES) rp[i] = s[threadIdx.x] - v;  // exclusive
  if (threadIdx.x == 255) bsum[blockIdx.x] = s[255];
}

__global__ void scan2_k(int* __restrict__ bsum) {
  __shared__ int s[512];
  int v = (threadIdx.x < NB) ? bsum[threadIdx.x] : 0;
  s[threadIdx.x] = v;
  __syncthreads();
  for (int o = 1; o < 512; o <<= 1) {
    int t = (threadIdx.x >= o) ? s[threadIdx.x - o] : 0;
    __syncthreads();
    s[threadIdx.x] += t;
    __syncthreads();
  }
  if (threadIdx.x < NB) bsum[threadIdx.x] = s[threadIdx.x] - v;  // exclusive
}

__global__ void scan3_k(int* __restrict__ rp, const int* __restrict__ bsum,
                        int* __restrict__ wpos) {
  int i = blockIdx.x * 256 + threadIdx.x;
  if (i < N_NODES) {
    int v = rp[i] + bsum[blockIdx.x];
    rp[i] = v;
    wpos[i] = v;
  }
  if (i == 0) rp[N_NODES] = N_EDGES;
}

// ---------------- CSR fill ----------------
__global__ void fill_k(const int* __restrict__ src, const int* __restrict__ dst,
                       int* __restrict__ wpos, int* __restrict__ col) {
  int e = blockIdx.x * blockDim.x + threadIdx.x;
  if (e < N_EDGES) {
    int slot = atomicAdd(&wpos[dst[e]], 1);
    col[slot] = src[e];
  }
}

// ---------------- fused gather + mean + dual-GEMM (+ optional pool) ----------------
// wave per contiguous node chunk; lane = out-channel.
// W rows live in registers (64+64 VGPR); input vector broadcast via readlane
// with compile-time lane index -> v_fmac with SGPR operand, zero DS ops.
// MODE 0: write h rows.  MODE 1: run-length pool into gsum/gcnt.
template <int MODE>
__global__ __launch_bounds__(256) void layer_k(
    const float* __restrict__ in, const int* __restrict__ rowptr,
    const int* __restrict__ col, const float* __restrict__ Wl,
    const float* __restrict__ bl, const float* __restrict__ Wr,
    float* __restrict__ outh, const int* __restrict__ batch,
    float* __restrict__ gsum, int* __restrict__ gcnt) {
  const int lane = threadIdx.x & 63;
  // stage W into registers: lane j holds Wl[j][0..63], Wr[j][0..63]
  float Wlr[CH], Wrr[CH];
  const float4* Wl4 = reinterpret_cast<const float4*>(Wl);
  const float4* Wr4 = reinterpret_cast<const float4*>(Wr);
#pragma unroll
  for (int q = 0; q < 16; ++q) {
    float4 w1 = Wl4[lane * 16 + q];
    float4 w2 = Wr4[lane * 16 + q];
    Wlr[4 * q + 0] = w1.x; Wlr[4 * q + 1] = w1.y;
    Wlr[4 * q + 2] = w1.z; Wlr[4 * q + 3] = w1.w;
    Wrr[4 * q + 0] = w2.x; Wrr[4 * q + 1] = w2.y;
    Wrr[4 * q + 2] = w2.z; Wrr[4 * q + 3] = w2.w;
  }
  const float biasv = bl[lane];

  const int wid = blockIdx.x * (blockDim.x >> 6) + (threadIdx.x >> 6);
  const int nw = gridDim.x * (blockDim.x >> 6);
  const int per = (N_NODES + nw - 1) / nw;
  int ns = wid * per;
  int ne = ns + per;
  if (ne > N_NODES) ne = N_NODES;
  if (ns >= ne) return;

  int curg = -1;
  float paccv = 0.f;
  int pcnt = 0;

  for (int n = ns; n < ne; ++n) {
    const int eb = rowptr[n], ee = rowptr[n + 1];
    // gather neighbor mean (4-way unrolled for MLP)
    float a0 = 0.f, a1 = 0.f, a2 = 0.f, a3 = 0.f;
    int i = eb;
    for (; i + 4 <= ee; i += 4) {
      int c0 = col[i], c1 = col[i + 1], c2 = col[i + 2], c3 = col[i + 3];
      a0 += in[(size_t)c0 * CH + lane];
      a1 += in[(size_t)c1 * CH + lane];
      a2 += in[(size_t)c2 * CH + lane];
      a3 += in[(size_t)c3 * CH + lane];
    }
    for (; i < ee; ++i) a0 += in[(size_t)col[i] * CH + lane];
    const int deg = ee - eb;
    const float inv = deg > 0 ? 1.f / (float)deg : 1.f;
    const float a = ((a0 + a1) + (a2 + a3)) * inv;
    const float xv = in[(size_t)n * CH + lane];

    // dual 64x64 matmul: 4 independent FMA chains, readlane broadcast
    float acc0 = biasv, acc1 = 0.f, acc2 = 0.f, acc3 = 0.f;
#pragma unroll
    for (int k = 0; k < CH; k += 2) {
      float sa0 = bcast(a, k), sa1 = bcast(a, k + 1);
      float sx0 = bcast(xv, k), sx1 = bcast(xv, k + 1);
      acc0 = fmaf(sa0, Wlr[k], acc0);
      acc1 = fmaf(sa1, Wlr[k + 1], acc1);
      acc2 = fmaf(sx0, Wrr[k], acc2);
      acc3 = fmaf(sx1, Wrr[k + 1], acc3);
    }
    const float r = fmaxf((acc0 + acc1) + (acc2 + acc3), 0.f);

    if (MODE == 0) {
      outh[(size_t)n * CH + lane] = r;
    } else {
      int g = batch[n];
      if (g != curg) {
        if (curg >= 0) {
          atomicAdd(&gsum[curg * CH + lane], paccv);
          if (lane == 0) atomicAdd(&gcnt[curg], pcnt);
        }
        curg = g;
        paccv = 0.f;
        pcnt = 0;
      }
      paccv += r;
      pcnt++;
    }
  }
  if (MODE == 1 && curg >= 0) {
    atomicAdd(&gsum[curg * CH + lane], paccv);
    if (lane == 0) atomicAdd(&gcnt[curg], pcnt);
  }
}

// ---------------- final projection ----------------
__global__ void final_k(const float* __restrict__ gsum, const int* __restrict__ gcnt,
                        const float* __restrict__ Wc, const float* __restrict__ bc,
                        float* __restrict__ out) {
  __shared__ float Wcs[OC * CH];
  __shared__ float bcs[OC];
  for (int i = threadIdx.x; i < OC * CH; i += blockDim.x) Wcs[i] = Wc[i];
  if (threadIdx.x < OC) bcs[threadIdx.x] = bc[threadIdx.x];
  __syncthreads();
  int g = threadIdx.x;  // 256 threads = 256 graphs
  float c = (float)gcnt[g];
  float inv = c > 0.f ? 1.f / c : 1.f;
  float gr[CH];
#pragma unroll
  for (int k = 0; k < CH; ++k) gr[k] = gsum[g * CH + k] * inv;
#pragma unroll
  for (int o = 0; o < OC; ++o) {
    float acc = bcs[o];
#pragma unroll
    for (int k = 0; k < CH; ++k) acc += gr[k] * Wcs[o * CH + k];
    out[g * OC + o] = acc;
  }
}

extern "C" void kernel_launch(void* const* d_in, const int* in_sizes, int n_in,
                              void* d_out, int out_size, void* d_ws, size_t ws_size,
                              hipStream_t stream) {
  const float* x   = (const float*)d_in[0];
  const int*   ei  = (const int*)d_in[1];
  const int*   bat = (const int*)d_in[2];
  const float* W1l = (const float*)d_in[3];
  const float* b1l = (const float*)d_in[4];
  const float* W1r = (const float*)d_in[5];
  const float* W2l = (const float*)d_in[6];
  const float* b2l = (const float*)d_in[7];
  const float* W2r = (const float*)d_in[8];
  const float* Wc  = (const float*)d_in[9];
  const float* bc  = (const float*)d_in[10];
  float* out = (float*)d_out;

  char* ws = (char*)d_ws;
  float* h1   = (float*)(ws + 0);          // 25,600,000 B
  int*   cnt  = (int*)(ws + 25600000);     //    400,000 B
  int*   rp   = (int*)(ws + 26000000);     //    400,004 B
  int*   wpos = (int*)(ws + 26400512);     //    400,000 B
  int*   col  = (int*)(ws + 26800512);     //  4,800,000 B
  int*   bsum = (int*)(ws + 31600512);     //      2,048 B
  float* gsum = (float*)(ws + 31602560);   //     65,536 B
  int*   gcnt = (int*)(ws + 31668096);     //      1,024 B

  const int* src = ei;
  const int* dst = ei + N_EDGES;

  hipMemsetAsync(cnt, 0, (size_t)N_NODES * sizeof(int), stream);
  hipMemsetAsync(gsum, 0, (size_t)NG * CH * sizeof(float) + NG * sizeof(int), stream);

  // ---- CSR build ----
  count_k<<<(N_EDGES + 255) / 256, 256, 0, stream>>>(dst, cnt);
  scan1_k<<<NB, 256, 0, stream>>>(cnt, rp, bsum);
  scan2_k<<<1, 512, 0, stream>>>(bsum);
  scan3_k<<<NB, 256, 0, stream>>>(rp, bsum, wpos);
  fill_k<<<(N_EDGES + 255) / 256, 256, 0, stream>>>(src, dst, wpos, col);

  // ---- layer 1: x -> h1 ----
  layer_k<0><<<768, 256, 0, stream>>>(x, rp, col, W1l, b1l, W1r, h1,
                                      nullptr, nullptr, nullptr);
  // ---- layer 2 fused with pool: h1 -> gsum/gcnt ----
  layer_k<1><<<768, 256, 0, stream>>>(h1, rp, col, W2l, b2l, W2r, nullptr,
                                      bat, gsum, gcnt);
  // ---- classify ----
  final_k<<<1, 256, 0, stream>>>(gsum, gcnt, Wc, bc, out);
}

// Round 3
// 376.398 us; speedup vs baseline: 2.5391x; 1.1977x over previous
//
#include <hip/hip_runtime.h>

#define N_NODES 100000
#define N_EDGES 1200000
#define CH 64
#define NG 256
#define OC 8
#define NB 391  // ceil(N_NODES/256)

__device__ __forceinline__ float bcast(float v, int k) {
  return __int_as_float(__builtin_amdgcn_readlane(__float_as_int(v), k));
}

// ---------------- degree count ----------------
__global__ void count_k(const int* __restrict__ dst, int* __restrict__ cnt) {
  int e = blockIdx.x * blockDim.x + threadIdx.x;
  if (e < N_EDGES) atomicAdd(&cnt[dst[e]], 1);
}

// ---------------- 3-kernel exclusive scan: cnt -> rowptr ----------------
__global__ void scan1_k(const int* __restrict__ cnt, int* __restrict__ rp,
                        int* __restrict__ bsum) {
  __shared__ int s[256];
  int i = blockIdx.x * 256 + threadIdx.x;
  int v = (i < N_NODES) ? cnt[i] : 0;
  s[threadIdx.x] = v;
  __syncthreads();
  for (int o = 1; o < 256; o <<= 1) {
    int t = (threadIdx.x >= o) ? s[threadIdx.x - o] : 0;
    __syncthreads();
    s[threadIdx.x] += t;
    __syncthreads();
  }
  if (i < N_NODES) rp[i] = s[threadIdx.x] - v;  // exclusive
  if (threadIdx.x == 255) bsum[blockIdx.x] = s[255];
}

__global__ void scan2_k(int* __restrict__ bsum) {
  __shared__ int s[512];
  int v = (threadIdx.x < NB) ? bsum[threadIdx.x] : 0;
  s[threadIdx.x] = v;
  __syncthreads();
  for (int o = 1; o < 512; o <<= 1) {
    int t = (threadIdx.x >= o) ? s[threadIdx.x - o] : 0;
    __syncthreads();
    s[threadIdx.x] += t;
    __syncthreads();
  }
  if (threadIdx.x < NB) bsum[threadIdx.x] = s[threadIdx.x] - v;  // exclusive
}

__global__ void scan3_k(int* __restrict__ rp, const int* __restrict__ bsum,
                        int* __restrict__ wpos) {
  int i = blockIdx.x * 256 + threadIdx.x;
  if (i < N_NODES) {
    int v = rp[i] + bsum[blockIdx.x];
    rp[i] = v;
    wpos[i] = v;
  }
  if (i == 0) rp[N_NODES] = N_EDGES;
}

// ---------------- CSR fill ----------------
__global__ void fill_k(const int* __restrict__ src, const int* __restrict__ dst,
                       int* __restrict__ wpos, int* __restrict__ col) {
  int e = blockIdx.x * blockDim.x + threadIdx.x;
  if (e < N_EDGES) {
    int slot = atomicAdd(&wpos[dst[e]], 1);
    col[slot] = src[e];
  }
}

// ---------------- dense dual transform: outl = in@Wl^T, outr = in@Wr^T ----------------
// wave per node; lane = out-channel; W rows in registers; readlane broadcast.
// NO bias here (bias is added post-aggregation in gather_k; mean preserves it).
// outr may alias in (layer-2 in-place): row is fully read before written.
__global__ __launch_bounds__(256) void transform_k(
    const float* in, const float* __restrict__ Wl, const float* __restrict__ Wr,
    float* __restrict__ outl, float* outr) {
  const int lane = threadIdx.x & 63;
  float Wlr[CH], Wrr[CH];
  const float4* Wl4 = reinterpret_cast<const float4*>(Wl);
  const float4* Wr4 = reinterpret_cast<const float4*>(Wr);
#pragma unroll
  for (int q = 0; q < 16; ++q) {
    float4 w1 = Wl4[lane * 16 + q];
    float4 w2 = Wr4[lane * 16 + q];
    Wlr[4 * q + 0] = w1.x; Wlr[4 * q + 1] = w1.y;
    Wlr[4 * q + 2] = w1.z; Wlr[4 * q + 3] = w1.w;
    Wrr[4 * q + 0] = w2.x; Wrr[4 * q + 1] = w2.y;
    Wrr[4 * q + 2] = w2.z; Wrr[4 * q + 3] = w2.w;
  }
  const int wid = blockIdx.x * (blockDim.x >> 6) + (threadIdx.x >> 6);
  const int nw = gridDim.x * (blockDim.x >> 6);
  const int per = (N_NODES + nw - 1) / nw;
  int ns = wid * per;
  int ne = ns + per;
  if (ne > N_NODES) ne = N_NODES;
  for (int n = ns; n < ne; ++n) {
    const float xv = in[(size_t)n * CH + lane];
    float l0 = 0.f, l1 = 0.f, r0 = 0.f, r1 = 0.f;
#pragma unroll
    for (int k = 0; k < CH; k += 2) {
      float s0 = bcast(xv, k);
      float s1 = bcast(xv, k + 1);
      l0 = fmaf(s0, Wlr[k], l0);
      l1 = fmaf(s1, Wlr[k + 1], l1);
      r0 = fmaf(s0, Wrr[k], r0);
      r1 = fmaf(s1, Wrr[k + 1], r1);
    }
    outl[(size_t)n * CH + lane] = l0 + l1;
    outr[(size_t)n * CH + lane] = r0 + r1;  // in-place safe: xv already read
  }
}

// ---------------- gather + mean + bias + relu (+ optional pool) ----------------
// h[n] = relu( inv*sum_{i} gl[col[i]] + bl + gr[n] ).
// MODE 0: write h over gr[n] (in-place).  MODE 1: run-length pool.
template <int MODE>
__global__ __launch_bounds__(256) void gather_k(
    const float* __restrict__ gl, const float* gr, const float* __restrict__ bl,
    const int* __restrict__ rowptr, const int* __restrict__ col,
    float* outh, const int* __restrict__ batch,
    float* __restrict__ gsum, int* __restrict__ gcnt) {
  const int lane = threadIdx.x & 63;
  const float biasv = bl[lane];
  const int wid = blockIdx.x * (blockDim.x >> 6) + (threadIdx.x >> 6);
  const int nw = gridDim.x * (blockDim.x >> 6);
  const int per = (N_NODES + nw - 1) / nw;
  int ns = wid * per;
  int ne = ns + per;
  if (ne > N_NODES) ne = N_NODES;
  if (ns >= ne) return;

  int curg = -1;
  float paccv = 0.f;
  int pcnt = 0;

  for (int n = ns; n < ne; ++n) {
    const int eb = rowptr[n], ee = rowptr[n + 1];
    float a0 = 0.f, a1 = 0.f, a2 = 0.f, a3 = 0.f;
    int i = eb;
    for (; i + 4 <= ee; i += 4) {
      int c0 = col[i], c1 = col[i + 1], c2 = col[i + 2], c3 = col[i + 3];
      a0 += gl[(size_t)c0 * CH + lane];
      a1 += gl[(size_t)c1 * CH + lane];
      a2 += gl[(size_t)c2 * CH + lane];
      a3 += gl[(size_t)c3 * CH + lane];
    }
    for (; i < ee; ++i) a0 += gl[(size_t)col[i] * CH + lane];
    const int deg = ee - eb;
    const float inv = deg > 0 ? 1.f / (float)deg : 1.f;
    const float r =
        fmaxf(fmaf(((a0 + a1) + (a2 + a3)), inv,
                   biasv + gr[(size_t)n * CH + lane]),
              0.f);
    if (MODE == 0) {
      outh[(size_t)n * CH + lane] = r;  // in-place over gr[n]
    } else {
      int g = batch[n];
      if (g != curg) {
        if (curg >= 0) {
          atomicAdd(&gsum[curg * CH + lane], paccv);
          if (lane == 0) atomicAdd(&gcnt[curg], pcnt);
        }
        curg = g;
        paccv = 0.f;
        pcnt = 0;
      }
      paccv += r;
      pcnt++;
    }
  }
  if (MODE == 1 && curg >= 0) {
    atomicAdd(&gsum[curg * CH + lane], paccv);
    if (lane == 0) atomicAdd(&gcnt[curg], pcnt);
  }
}

// ---------------- final projection ----------------
__global__ void final_k(const float* __restrict__ gsum, const int* __restrict__ gcnt,
                        const float* __restrict__ Wc, const float* __restrict__ bc,
                        float* __restrict__ out) {
  __shared__ float Wcs[OC * CH];
  __shared__ float bcs[OC];
  for (int i = threadIdx.x; i < OC * CH; i += blockDim.x) Wcs[i] = Wc[i];
  if (threadIdx.x < OC) bcs[threadIdx.x] = bc[threadIdx.x];
  __syncthreads();
  int g = threadIdx.x;  // 256 threads = 256 graphs
  float c = (float)gcnt[g];
  float inv = c > 0.f ? 1.f / c : 1.f;
  float gr[CH];
#pragma unroll
  for (int k = 0; k < CH; ++k) gr[k] = gsum[g * CH + k] * inv;
#pragma unroll
  for (int o = 0; o < OC; ++o) {
    float acc = bcs[o];
#pragma unroll
    for (int k = 0; k < CH; ++k) acc += gr[k] * Wcs[o * CH + k];
    out[g * OC + o] = acc;
  }
}

extern "C" void kernel_launch(void* const* d_in, const int* in_sizes, int n_in,
                              void* d_out, int out_size, void* d_ws, size_t ws_size,
                              hipStream_t stream) {
  const float* x   = (const float*)d_in[0];
  const int*   ei  = (const int*)d_in[1];
  const int*   bat = (const int*)d_in[2];
  const float* W1l = (const float*)d_in[3];
  const float* b1l = (const float*)d_in[4];
  const float* W1r = (const float*)d_in[5];
  const float* W2l = (const float*)d_in[6];
  const float* b2l = (const float*)d_in[7];
  const float* W2r = (const float*)d_in[8];
  const float* Wc  = (const float*)d_in[9];
  const float* bc  = (const float*)d_in[10];
  float* out = (float*)d_out;

  char* ws = (char*)d_ws;
  // BUF1: xl -> h2l          BUF2: xr -> h1 -> h2r (row-wise in-place)
  float* buf1 = (float*)(ws + 0);              // 25,600,000 B
  float* buf2 = (float*)(ws + 25600000);       // 25,600,000 B
  int*   rp   = (int*)(ws + 51200000);         //    400,004 B
  int*   cwp  = (int*)(ws + 51600128);         //    400,000 B (cnt, then wpos)
  int*   col  = (int*)(ws + 52000128);         //  4,800,000 B
  int*   bsum = (int*)(ws + 56800128);         //      2,048 B
  float* gsum = (float*)(ws + 56802176);       //     65,536 B
  int*   gcnt = (int*)(ws + 56867712);         //      1,024 B

  const int* src = ei;
  const int* dst = ei + N_EDGES;

  hipMemsetAsync(cwp, 0, (size_t)N_NODES * sizeof(int), stream);
  hipMemsetAsync(gsum, 0, (size_t)NG * CH * sizeof(float) + NG * sizeof(int), stream);

  // ---- CSR build ----
  count_k<<<(N_EDGES + 255) / 256, 256, 0, stream>>>(dst, cwp);
  scan1_k<<<NB, 256, 0, stream>>>(cwp, rp, bsum);
  scan2_k<<<1, 512, 0, stream>>>(bsum);
  scan3_k<<<NB, 256, 0, stream>>>(rp, bsum, cwp);  // cwp now = wpos
  fill_k<<<(N_EDGES + 255) / 256, 256, 0, stream>>>(src, dst, cwp, col);

  // ---- layer 1 ----
  transform_k<<<1024, 256, 0, stream>>>(x, W1l, W1r, buf1, buf2);       // xl, xr
  gather_k<0><<<2048, 256, 0, stream>>>(buf1, buf2, b1l, rp, col, buf2,
                                        nullptr, nullptr, nullptr);     // h1 in buf2
  // ---- layer 2 ----
  transform_k<<<1024, 256, 0, stream>>>(buf2, W2l, W2r, buf1, buf2);    // h2l, h2r
  gather_k<1><<<2048, 256, 0, stream>>>(buf1, buf2, b2l, rp, col, nullptr,
                                        bat, gsum, gcnt);               // pool
  // ---- classify ----
  final_k<<<1, 256, 0, stream>>>(gsum, gcnt, Wc, bc, out);
}

// Round 5
// 277.753 us; speedup vs baseline: 3.4409x; 1.3552x over previous
//
#include <hip/hip_runtime.h>

#define N_NODES 100000
#define N_EDGES 1200000
#define CH 64
#define NG 256
#define OC 8
#define NBUK 196        // ceil(N_NODES/512)
#define BINCHUNK 4096
#define NBLKA 293       // ceil(N_EDGES/BINCHUNK)

__device__ __forceinline__ float bcast(float v, int k) {
  return __int_as_float(__builtin_amdgcn_readlane(__float_as_int(v), k));
}

// ---------------- pass A1: per-bucket totals (dst>>9) ----------------
__global__ __launch_bounds__(256) void countA_k(const int* __restrict__ dst,
                                                int* __restrict__ gbase) {
  __shared__ int hist[NBUK];
  for (int i = threadIdx.x; i < NBUK; i += 256) hist[i] = 0;
  __syncthreads();
  const int cs = blockIdx.x * BINCHUNK;
  int ce = cs + BINCHUNK;
  if (ce > N_EDGES) ce = N_EDGES;
  for (int e = cs + threadIdx.x; e < ce; e += 256)
    atomicAdd(&hist[dst[e] >> 9], 1);
  __syncthreads();
  for (int b = threadIdx.x; b < NBUK; b += 256) {
    int c = hist[b];
    if (c) atomicAdd(&gbase[b], c);
  }
}

// ---------------- pass B: exclusive scan -> boff; cursor = boff ----------------
__global__ void scanB_k(const int* __restrict__ gbase, int* __restrict__ boff,
                        int* __restrict__ cursor) {
  __shared__ int s[256];
  int v = (threadIdx.x < NBUK) ? gbase[threadIdx.x] : 0;
  s[threadIdx.x] = v;
  __syncthreads();
  for (int o = 1; o < 256; o <<= 1) {
    int t = (threadIdx.x >= o) ? s[threadIdx.x - o] : 0;
    __syncthreads();
    s[threadIdx.x] += t;
    __syncthreads();
  }
  if (threadIdx.x < NBUK) {
    int ex = s[threadIdx.x] - v;
    boff[threadIdx.x] = ex;
    cursor[threadIdx.x] = ex;
  }
  if (threadIdx.x == NBUK - 1) boff[NBUK] = s[threadIdx.x];
}

// ---------------- pass A2: scatter packed edges into bucket regions ----------------
__global__ __launch_bounds__(256) void scatterA_k(const int* __restrict__ src,
                                                  const int* __restrict__ dst,
                                                  int* __restrict__ cursor,
                                                  int* __restrict__ tmp) {
  __shared__ int hist[NBUK];
  for (int i = threadIdx.x; i < NBUK; i += 256) hist[i] = 0;
  __syncthreads();
  const int cs = blockIdx.x * BINCHUNK;
  int ce = cs + BINCHUNK;
  if (ce > N_EDGES) ce = N_EDGES;
  for (int e = cs + threadIdx.x; e < ce; e += 256)
    atomicAdd(&hist[dst[e] >> 9], 1);
  __syncthreads();
  // claim contiguous global runs (cursor holds scanned offsets)
  for (int b = threadIdx.x; b < NBUK; b += 256) {
    int c = hist[b];
    hist[b] = c ? atomicAdd(&cursor[b], c) : 0;
  }
  __syncthreads();
  for (int e = cs + threadIdx.x; e < ce; e += 256) {
    int d = dst[e];
    int slot = atomicAdd(&hist[d >> 9], 1);
    tmp[slot] = (src[e] << 9) | (d & 511);
  }
}

// ---------------- pass C: per-bucket fine CSR (rowptr + col) ----------------
__global__ __launch_bounds__(512) void csrC_k(const int* __restrict__ tmp,
                                              const int* __restrict__ boff,
                                              int* __restrict__ rp,
                                              int* __restrict__ col) {
  __shared__ int lh[512];
  __shared__ int s[512];
  const int b = blockIdx.x;
  const int tid = threadIdx.x;
  const int eb = boff[b], ee = boff[b + 1];
  lh[tid] = 0;
  __syncthreads();
  for (int e = eb + tid; e < ee; e += 512) atomicAdd(&lh[tmp[e] & 511], 1);
  __syncthreads();
  int v = lh[tid];
  s[tid] = v;
  __syncthreads();
  for (int o = 1; o < 512; o <<= 1) {
    int t = (tid >= o) ? s[tid - o] : 0;
    __syncthreads();
    s[tid] += t;
    __syncthreads();
  }
  const int base = eb + s[tid] - v;  // bucket offset + within-bucket exclusive
  const int node = b * 512 + tid;
  if (node < N_NODES) rp[node] = base;
  if (b == 0 && tid == 0) rp[N_NODES] = N_EDGES;
  lh[tid] = base;  // reuse as cursor
  __syncthreads();
  for (int e = eb + tid; e < ee; e += 512) {
    int p = tmp[e];
    int slot = atomicAdd(&lh[p & 511], 1);
    col[slot] = p >> 9;
  }
}

// ---------------- dense dual transform: outl = in@Wl^T, outr = in@Wr^T ----------------
__global__ __launch_bounds__(256) void transform_k(
    const float* in, const float* __restrict__ Wl, const float* __restrict__ Wr,
    float* __restrict__ outl, float* outr) {
  const int lane = threadIdx.x & 63;
  float Wlr[CH], Wrr[CH];
  const float4* Wl4 = reinterpret_cast<const float4*>(Wl);
  const float4* Wr4 = reinterpret_cast<const float4*>(Wr);
#pragma unroll
  for (int q = 0; q < 16; ++q) {
    float4 w1 = Wl4[lane * 16 + q];
    float4 w2 = Wr4[lane * 16 + q];
    Wlr[4 * q + 0] = w1.x; Wlr[4 * q + 1] = w1.y;
    Wlr[4 * q + 2] = w1.z; Wlr[4 * q + 3] = w1.w;
    Wrr[4 * q + 0] = w2.x; Wrr[4 * q + 1] = w2.y;
    Wrr[4 * q + 2] = w2.z; Wrr[4 * q + 3] = w2.w;
  }
  const int wid = blockIdx.x * (blockDim.x >> 6) + (threadIdx.x >> 6);
  const int nw = gridDim.x * (blockDim.x >> 6);
  const int per = (N_NODES + nw - 1) / nw;
  int ns = wid * per;
  int ne = ns + per;
  if (ne > N_NODES) ne = N_NODES;
  for (int n = ns; n < ne; ++n) {
    const float xv = in[(size_t)n * CH + lane];
    float l0 = 0.f, l1 = 0.f, r0 = 0.f, r1 = 0.f;
#pragma unroll
    for (int k = 0; k < CH; k += 2) {
      float s0 = bcast(xv, k);
      float s1 = bcast(xv, k + 1);
      l0 = fmaf(s0, Wlr[k], l0);
      l1 = fmaf(s1, Wlr[k + 1], l1);
      r0 = fmaf(s0, Wrr[k], r0);
      r1 = fmaf(s1, Wrr[k + 1], r1);
    }
    outl[(size_t)n * CH + lane] = l0 + l1;
    outr[(size_t)n * CH + lane] = r0 + r1;  // in-place safe: xv already read
  }
}

// ---------------- gather + mean + bias + relu (+ optional pool) ----------------
template <int MODE>
__global__ __launch_bounds__(256) void gather_k(
    const float* __restrict__ gl, const float* gr, const float* __restrict__ bl,
    const int* __restrict__ rowptr, const int* __restrict__ col,
    float* outh, const int* __restrict__ batch,
    float* __restrict__ gsum, int* __restrict__ gcnt) {
  const int lane = threadIdx.x & 63;
  const float biasv = bl[lane];
  const int wid = blockIdx.x * (blockDim.x >> 6) + (threadIdx.x >> 6);
  const int nw = gridDim.x * (blockDim.x >> 6);
  const int per = (N_NODES + nw - 1) / nw;
  int ns = wid * per;
  int ne = ns + per;
  if (ne > N_NODES) ne = N_NODES;
  if (ns >= ne) return;

  int curg = -1;
  float paccv = 0.f;
  int pcnt = 0;

  for (int n = ns; n < ne; ++n) {
    const int eb = rowptr[n], ee = rowptr[n + 1];
    float a0 = 0.f, a1 = 0.f, a2 = 0.f, a3 = 0.f;
    int i = eb;
    for (; i + 4 <= ee; i += 4) {
      int c0 = col[i], c1 = col[i + 1], c2 = col[i + 2], c3 = col[i + 3];
      a0 += gl[(size_t)c0 * CH + lane];
      a1 += gl[(size_t)c1 * CH + lane];
      a2 += gl[(size_t)c2 * CH + lane];
      a3 += gl[(size_t)c3 * CH + lane];
    }
    for (; i < ee; ++i) a0 += gl[(size_t)col[i] * CH + lane];
    const int deg = ee - eb;
    const float inv = deg > 0 ? 1.f / (float)deg : 1.f;
    const float r =
        fmaxf(fmaf(((a0 + a1) + (a2 + a3)), inv,
                   biasv + gr[(size_t)n * CH + lane]),
              0.f);
    if (MODE == 0) {
      outh[(size_t)n * CH + lane] = r;
    } else {
      int g = batch[n];
      if (g != curg) {
        if (curg >= 0) {
          atomicAdd(&gsum[curg * CH + lane], paccv);
          if (lane == 0) atomicAdd(&gcnt[curg], pcnt);
        }
        curg = g;
        paccv = 0.f;
        pcnt = 0;
      }
      paccv += r;
      pcnt++;
    }
  }
  if (MODE == 1 && curg >= 0) {
    atomicAdd(&gsum[curg * CH + lane], paccv);
    if (lane == 0) atomicAdd(&gcnt[curg], pcnt);
  }
}

// ---------------- final projection ----------------
__global__ void final_k(const float* __restrict__ gsum, const int* __restrict__ gcnt,
                        const float* __restrict__ Wc, const float* __restrict__ bc,
                        float* __restrict__ out) {
  __shared__ float Wcs[OC * CH];
  __shared__ float bcs[OC];
  for (int i = threadIdx.x; i < OC * CH; i += blockDim.x) Wcs[i] = Wc[i];
  if (threadIdx.x < OC) bcs[threadIdx.x] = bc[threadIdx.x];
  __syncthreads();
  int g = threadIdx.x;
  float c = (float)gcnt[g];
  float inv = c > 0.f ? 1.f / c : 1.f;
  float gr[CH];
#pragma unroll
  for (int k = 0; k < CH; ++k) gr[k] = gsum[g * CH + k] * inv;
#pragma unroll
  for (int o = 0; o < OC; ++o) {
    float acc = bcs[o];
#pragma unroll
    for (int k = 0; k < CH; ++k) acc += gr[k] * Wcs[o * CH + k];
    out[g * OC + o] = acc;
  }
}

extern "C" void kernel_launch(void* const* d_in, const int* in_sizes, int n_in,
                              void* d_out, int out_size, void* d_ws, size_t ws_size,
                              hipStream_t stream) {
  const float* x   = (const float*)d_in[0];
  const int*   ei  = (const int*)d_in[1];
  const int*   bat = (const int*)d_in[2];
  const float* W1l = (const float*)d_in[3];
  const float* b1l = (const float*)d_in[4];
  const float* W1r = (const float*)d_in[5];
  const float* W2l = (const float*)d_in[6];
  const float* b2l = (const float*)d_in[7];
  const float* W2r = (const float*)d_in[8];
  const float* Wc  = (const float*)d_in[9];
  const float* bc  = (const float*)d_in[10];
  float* out = (float*)d_out;

  char* ws = (char*)d_ws;
  // buf1 first 4.8MB doubles as tmp during CSR build (dead before transforms)
  float* buf1  = (float*)(ws + 0);              // 25,600,000 B
  float* buf2  = (float*)(ws + 25600000);       // 25,600,000 B
  int*   tmp   = (int*)buf1;                    //  4,800,000 B (aliased)
  int*   rp    = (int*)(ws + 51200000);         //    400,128 B (incl pad)
  int*   col   = (int*)(ws + 51600128);         //  4,800,000 B
  int*   gbase = (int*)(ws + 56400128);         //      1,024 B
  int*   boff  = (int*)(ws + 56401152);         //      1,024 B
  int*   cursor= (int*)(ws + 56402176);         //      1,024 B
  float* gsum  = (float*)(ws + 56403200);       //     65,536 B
  int*   gcnt  = (int*)(ws + 56468736);         //      1,024 B

  const int* src = ei;
  const int* dst = ei + N_EDGES;

  hipMemsetAsync(gbase, 0, NBUK * sizeof(int), stream);
  hipMemsetAsync(gsum, 0, (size_t)NG * CH * sizeof(float) + NG * sizeof(int), stream);

  // ---- CSR build (bucketed counting sort, correct count->scan->scatter order) ----
  countA_k<<<NBLKA, 256, 0, stream>>>(dst, gbase);
  scanB_k<<<1, 256, 0, stream>>>(gbase, boff, cursor);
  scatterA_k<<<NBLKA, 256, 0, stream>>>(src, dst, cursor, tmp);
  csrC_k<<<NBUK, 512, 0, stream>>>(tmp, boff, rp, col);

  // ---- layer 1 ----
  transform_k<<<1024, 256, 0, stream>>>(x, W1l, W1r, buf1, buf2);       // xl, xr
  gather_k<0><<<2048, 256, 0, stream>>>(buf1, buf2, b1l, rp, col, buf2,
                                        nullptr, nullptr, nullptr);     // h1
  // ---- layer 2 ----
  transform_k<<<1024, 256, 0, stream>>>(buf2, W2l, W2r, buf1, buf2);    // h2l, h2r
  gather_k<1><<<2048, 256, 0, stream>>>(buf1, buf2, b2l, rp, col, nullptr,
                                        bat, gsum, gcnt);               // pool
  // ---- classify ----
  final_k<<<1, 256, 0, stream>>>(gsum, gcnt, Wc, bc, out);
}

// Round 6
// 257.600 us; speedup vs baseline: 3.7101x; 1.0782x over previous
//
#include <hip/hip_runtime.h>

#define N_NODES 100000
#define N_EDGES 1200000
#define CH 64
#define NG 256
#define OC 8
#define NBUK 196        // ceil(N_NODES/512)
#define BINCHUNK 4096
#define NBLKA 293       // ceil(N_EDGES/BINCHUNK)

typedef unsigned short ushort_t;
typedef unsigned int uint_t;

__device__ __forceinline__ float bcast(float v, int k) {
  return __int_as_float(__builtin_amdgcn_readlane(__float_as_int(v), k));
}
__device__ __forceinline__ ushort_t f2bf(float f) {  // RNE f32->bf16
  uint_t u = __float_as_uint(f);
  return (ushort_t)((u + 0x7FFFu + ((u >> 16) & 1u)) >> 16);
}
__device__ __forceinline__ float bf2f(ushort_t b) {
  return __uint_as_float(((uint_t)b) << 16);
}

// ---------------- pass A1: per-bucket totals (dst>>9) ----------------
__global__ __launch_bounds__(256) void countA_k(const int* __restrict__ dst,
                                                int* __restrict__ gbase) {
  __shared__ int hist[NBUK];
  for (int i = threadIdx.x; i < NBUK; i += 256) hist[i] = 0;
  __syncthreads();
  const int cs = blockIdx.x * BINCHUNK;
  int ce = cs + BINCHUNK;
  if (ce > N_EDGES) ce = N_EDGES;
  for (int e = cs + threadIdx.x; e < ce; e += 256)
    atomicAdd(&hist[dst[e] >> 9], 1);
  __syncthreads();
  for (int b = threadIdx.x; b < NBUK; b += 256) {
    int c = hist[b];
    if (c) atomicAdd(&gbase[b], c);
  }
}

// ---------------- pass B: exclusive scan -> boff; cursor = boff ----------------
__global__ void scanB_k(const int* __restrict__ gbase, int* __restrict__ boff,
                        int* __restrict__ cursor) {
  __shared__ int s[256];
  int v = (threadIdx.x < NBUK) ? gbase[threadIdx.x] : 0;
  s[threadIdx.x] = v;
  __syncthreads();
  for (int o = 1; o < 256; o <<= 1) {
    int t = (threadIdx.x >= o) ? s[threadIdx.x - o] : 0;
    __syncthreads();
    s[threadIdx.x] += t;
    __syncthreads();
  }
  if (threadIdx.x < NBUK) {
    int ex = s[threadIdx.x] - v;
    boff[threadIdx.x] = ex;
    cursor[threadIdx.x] = ex;
  }
  if (threadIdx.x == NBUK - 1) boff[NBUK] = s[threadIdx.x];
}

// ---------------- pass A2: scatter packed edges into bucket regions ----------------
__global__ __launch_bounds__(256) void scatterA_k(const int* __restrict__ src,
                                                  const int* __restrict__ dst,
                                                  int* __restrict__ cursor,
                                                  int* __restrict__ tmp) {
  __shared__ int hist[NBUK];
  for (int i = threadIdx.x; i < NBUK; i += 256) hist[i] = 0;
  __syncthreads();
  const int cs = blockIdx.x * BINCHUNK;
  int ce = cs + BINCHUNK;
  if (ce > N_EDGES) ce = N_EDGES;
  for (int e = cs + threadIdx.x; e < ce; e += 256)
    atomicAdd(&hist[dst[e] >> 9], 1);
  __syncthreads();
  for (int b = threadIdx.x; b < NBUK; b += 256) {
    int c = hist[b];
    hist[b] = c ? atomicAdd(&cursor[b], c) : 0;
  }
  __syncthreads();
  for (int e = cs + threadIdx.x; e < ce; e += 256) {
    int d = dst[e];
    int slot = atomicAdd(&hist[d >> 9], 1);
    tmp[slot] = (src[e] << 9) | (d & 511);
  }
}

// ---------------- pass C: per-bucket fine CSR (rowptr + col) ----------------
__global__ __launch_bounds__(512) void csrC_k(const int* __restrict__ tmp,
                                              const int* __restrict__ boff,
                                              int* __restrict__ rp,
                                              int* __restrict__ col) {
  __shared__ int lh[512];
  __shared__ int s[512];
  const int b = blockIdx.x;
  const int tid = threadIdx.x;
  const int eb = boff[b], ee = boff[b + 1];
  lh[tid] = 0;
  __syncthreads();
  for (int e = eb + tid; e < ee; e += 512) atomicAdd(&lh[tmp[e] & 511], 1);
  __syncthreads();
  int v = lh[tid];
  s[tid] = v;
  __syncthreads();
  for (int o = 1; o < 512; o <<= 1) {
    int t = (tid >= o) ? s[tid - o] : 0;
    __syncthreads();
    s[tid] += t;
    __syncthreads();
  }
  const int base = eb + s[tid] - v;
  const int node = b * 512 + tid;
  if (node < N_NODES) rp[node] = base;
  if (b == 0 && tid == 0) rp[N_NODES] = N_EDGES;
  lh[tid] = base;
  __syncthreads();
  for (int e = eb + tid; e < ee; e += 512) {
    int p = tmp[e];
    int slot = atomicAdd(&lh[p & 511], 1);
    col[slot] = p >> 9;
  }
}

// ---------------- dense dual transform: outl(bf16) = in@Wl^T, outr(f32) = in@Wr^T ----
__global__ __launch_bounds__(256) void transform_k(
    const float* in, const float* __restrict__ Wl, const float* __restrict__ Wr,
    ushort_t* __restrict__ outl, float* outr) {
  const int lane = threadIdx.x & 63;
  float Wlr[CH], Wrr[CH];
  const float4* Wl4 = reinterpret_cast<const float4*>(Wl);
  const float4* Wr4 = reinterpret_cast<const float4*>(Wr);
#pragma unroll
  for (int q = 0; q < 16; ++q) {
    float4 w1 = Wl4[lane * 16 + q];
    float4 w2 = Wr4[lane * 16 + q];
    Wlr[4 * q + 0] = w1.x; Wlr[4 * q + 1] = w1.y;
    Wlr[4 * q + 2] = w1.z; Wlr[4 * q + 3] = w1.w;
    Wrr[4 * q + 0] = w2.x; Wrr[4 * q + 1] = w2.y;
    Wrr[4 * q + 2] = w2.z; Wrr[4 * q + 3] = w2.w;
  }
  const int wid = blockIdx.x * (blockDim.x >> 6) + (threadIdx.x >> 6);
  const int nw = gridDim.x * (blockDim.x >> 6);
  const int per = (N_NODES + nw - 1) / nw;
  int ns = wid * per;
  int ne = ns + per;
  if (ne > N_NODES) ne = N_NODES;
  for (int n = ns; n < ne; ++n) {
    const float xv = in[(size_t)n * CH + lane];
    float l0 = 0.f, l1 = 0.f, r0 = 0.f, r1 = 0.f;
#pragma unroll
    for (int k = 0; k < CH; k += 2) {
      float s0 = bcast(xv, k);
      float s1 = bcast(xv, k + 1);
      l0 = fmaf(s0, Wlr[k], l0);
      l1 = fmaf(s1, Wlr[k + 1], l1);
      r0 = fmaf(s0, Wrr[k], r0);
      r1 = fmaf(s1, Wrr[k + 1], r1);
    }
    outl[(size_t)n * CH + lane] = f2bf(l0 + l1);
    outr[(size_t)n * CH + lane] = r0 + r1;  // in-place safe: xv already read
  }
}

// ---------------- gather(bf16) + mean + bias + relu (+ optional pool) ----------------
template <int MODE>
__global__ __launch_bounds__(256) void gather_k(
    const ushort_t* __restrict__ gl, const float* gr, const float* __restrict__ bl,
    const int* __restrict__ rowptr, const int* __restrict__ col,
    float* outh, const int* __restrict__ batch,
    float* __restrict__ gsum, int* __restrict__ gcnt) {
  const int lane = threadIdx.x & 63;
  const float biasv = bl[lane];
  const int wid = blockIdx.x * (blockDim.x >> 6) + (threadIdx.x >> 6);
  const int nw = gridDim.x * (blockDim.x >> 6);
  const int per = (N_NODES + nw - 1) / nw;
  int ns = wid * per;
  int ne = ns + per;
  if (ne > N_NODES) ne = N_NODES;
  if (ns >= ne) return;

  int curg = -1;
  float paccv = 0.f;
  int pcnt = 0;

  for (int n = ns; n < ne; ++n) {
    const int eb = rowptr[n], ee = rowptr[n + 1];
    float a0 = 0.f, a1 = 0.f, a2 = 0.f, a3 = 0.f;
    float a4 = 0.f, a5 = 0.f, a6 = 0.f, a7 = 0.f;
    int i = eb;
    for (; i + 8 <= ee; i += 8) {
      int c0 = col[i],     c1 = col[i + 1], c2 = col[i + 2], c3 = col[i + 3];
      int c4 = col[i + 4], c5 = col[i + 5], c6 = col[i + 6], c7 = col[i + 7];
      a0 += bf2f(gl[(size_t)c0 * CH + lane]);
      a1 += bf2f(gl[(size_t)c1 * CH + lane]);
      a2 += bf2f(gl[(size_t)c2 * CH + lane]);
      a3 += bf2f(gl[(size_t)c3 * CH + lane]);
      a4 += bf2f(gl[(size_t)c4 * CH + lane]);
      a5 += bf2f(gl[(size_t)c5 * CH + lane]);
      a6 += bf2f(gl[(size_t)c6 * CH + lane]);
      a7 += bf2f(gl[(size_t)c7 * CH + lane]);
    }
    for (; i + 4 <= ee; i += 4) {
      int c0 = col[i], c1 = col[i + 1], c2 = col[i + 2], c3 = col[i + 3];
      a0 += bf2f(gl[(size_t)c0 * CH + lane]);
      a1 += bf2f(gl[(size_t)c1 * CH + lane]);
      a2 += bf2f(gl[(size_t)c2 * CH + lane]);
      a3 += bf2f(gl[(size_t)c3 * CH + lane]);
    }
    for (; i < ee; ++i) a0 += bf2f(gl[(size_t)col[i] * CH + lane]);
    const int deg = ee - eb;
    const float inv = deg > 0 ? 1.f / (float)deg : 1.f;
    const float s = ((a0 + a1) + (a2 + a3)) + ((a4 + a5) + (a6 + a7));
    const float r =
        fmaxf(fmaf(s, inv, biasv + gr[(size_t)n * CH + lane]), 0.f);
    if (MODE == 0) {
      outh[(size_t)n * CH + lane] = r;
    } else {
      int g = batch[n];
      if (g != curg) {
        if (curg >= 0) {
          atomicAdd(&gsum[curg * CH + lane], paccv);
          if (lane == 0) atomicAdd(&gcnt[curg], pcnt);
        }
        curg = g;
        paccv = 0.f;
        pcnt = 0;
      }
      paccv += r;
      pcnt++;
    }
  }
  if (MODE == 1 && curg >= 0) {
    atomicAdd(&gsum[curg * CH + lane], paccv);
    if (lane == 0) atomicAdd(&gcnt[curg], pcnt);
  }
}

// ---------------- final projection ----------------
__global__ void final_k(const float* __restrict__ gsum, const int* __restrict__ gcnt,
                        const float* __restrict__ Wc, const float* __restrict__ bc,
                        float* __restrict__ out) {
  __shared__ float Wcs[OC * CH];
  __shared__ float bcs[OC];
  for (int i = threadIdx.x; i < OC * CH; i += blockDim.x) Wcs[i] = Wc[i];
  if (threadIdx.x < OC) bcs[threadIdx.x] = bc[threadIdx.x];
  __syncthreads();
  int g = threadIdx.x;
  float c = (float)gcnt[g];
  float inv = c > 0.f ? 1.f / c : 1.f;
  float gr[CH];
#pragma unroll
  for (int k = 0; k < CH; ++k) gr[k] = gsum[g * CH + k] * inv;
#pragma unroll
  for (int o = 0; o < OC; ++o) {
    float acc = bcs[o];
#pragma unroll
    for (int k = 0; k < CH; ++k) acc += gr[k] * Wcs[o * CH + k];
    out[g * OC + o] = acc;
  }
}

extern "C" void kernel_launch(void* const* d_in, const int* in_sizes, int n_in,
                              void* d_out, int out_size, void* d_ws, size_t ws_size,
                              hipStream_t stream) {
  const float* x   = (const float*)d_in[0];
  const int*   ei  = (const int*)d_in[1];
  const int*   bat = (const int*)d_in[2];
  const float* W1l = (const float*)d_in[3];
  const float* b1l = (const float*)d_in[4];
  const float* W1r = (const float*)d_in[5];
  const float* W2l = (const float*)d_in[6];
  const float* b2l = (const float*)d_in[7];
  const float* W2r = (const float*)d_in[8];
  const float* Wc  = (const float*)d_in[9];
  const float* bc  = (const float*)d_in[10];
  float* out = (float*)d_out;

  char* ws = (char*)d_ws;
  // buf1: tmp (CSR build) -> xl/h2l as bf16 (12.8 MB)
  // buf2: xr -> h1 -> h2r (f32, row-wise in-place)
  ushort_t* buf1 = (ushort_t*)(ws + 0);         // 12,800,000 B (bf16)
  float* buf2    = (float*)(ws + 25600000);     // 25,600,000 B
  int*   tmp     = (int*)(ws + 0);              //  4,800,000 B (aliased w/ buf1)
  int*   rp      = (int*)(ws + 51200000);       //    400,128 B (incl pad)
  int*   col     = (int*)(ws + 51600128);       //  4,800,000 B
  int*   gbase   = (int*)(ws + 56400128);       //      1,024 B
  int*   boff    = (int*)(ws + 56401152);       //      1,024 B
  int*   cursor  = (int*)(ws + 56402176);       //      1,024 B
  float* gsum    = (float*)(ws + 56403200);     //     65,536 B
  int*   gcnt    = (int*)(ws + 56468736);       //      1,024 B

  const int* src = ei;
  const int* dst = ei + N_EDGES;

  hipMemsetAsync(gbase, 0, NBUK * sizeof(int), stream);
  hipMemsetAsync(gsum, 0, (size_t)NG * CH * sizeof(float) + NG * sizeof(int), stream);

  // ---- CSR build (bucketed counting sort) ----
  countA_k<<<NBLKA, 256, 0, stream>>>(dst, gbase);
  scanB_k<<<1, 256, 0, stream>>>(gbase, boff, cursor);
  scatterA_k<<<NBLKA, 256, 0, stream>>>(src, dst, cursor, tmp);
  csrC_k<<<NBUK, 512, 0, stream>>>(tmp, boff, rp, col);

  // ---- layer 1 ----
  transform_k<<<1024, 256, 0, stream>>>(x, W1l, W1r, buf1, buf2);       // xl(bf16), xr
  gather_k<0><<<2048, 256, 0, stream>>>(buf1, buf2, b1l, rp, col, buf2,
                                        nullptr, nullptr, nullptr);     // h1 (f32)
  // ---- layer 2 ----
  transform_k<<<1024, 256, 0, stream>>>(buf2, W2l, W2r, buf1, buf2);    // h2l(bf16), h2r
  gather_k<1><<<2048, 256, 0, stream>>>(buf1, buf2, b2l, rp, col, nullptr,
                                        bat, gsum, gcnt);               // pool
  // ---- classify ----
  final_k<<<1, 256, 0, stream>>>(gsum, gcnt, Wc, bc, out);
}

// Round 7
// 232.816 us; speedup vs baseline: 4.1050x; 1.1065x over previous
//
#include <hip/hip_runtime.h>

#define N_NODES 100000
#define N_EDGES 1200000
#define CH 64
#define NG 256
#define OC 8
#define NBUK 196        // ceil(N_NODES/512)
#define BINCHUNK 4096
#define NBLKA 293       // ceil(N_EDGES/BINCHUNK)
#define NSTRIP 6250     // N_NODES/16 (exact)

typedef unsigned short ushort_t;
typedef unsigned int uint_t;
typedef __attribute__((ext_vector_type(8))) short bf16x8;
typedef __attribute__((ext_vector_type(4))) float f32x4;

__device__ __forceinline__ ushort_t f2bf(float f) {  // RNE f32->bf16
  uint_t u = __float_as_uint(f);
  return (ushort_t)((u + 0x7FFFu + ((u >> 16) & 1u)) >> 16);
}
__device__ __forceinline__ float bf2f(ushort_t b) {
  return __uint_as_float(((uint_t)b) << 16);
}

// ---------------- pass A1: per-bucket totals (dst>>9) ----------------
__global__ __launch_bounds__(256) void countA_k(const int* __restrict__ dst,
                                                int* __restrict__ gbase) {
  __shared__ int hist[NBUK];
  for (int i = threadIdx.x; i < NBUK; i += 256) hist[i] = 0;
  __syncthreads();
  const int cs = blockIdx.x * BINCHUNK;
  int ce = cs + BINCHUNK;
  if (ce > N_EDGES) ce = N_EDGES;
  for (int e = cs + threadIdx.x; e < ce; e += 256)
    atomicAdd(&hist[dst[e] >> 9], 1);
  __syncthreads();
  for (int b = threadIdx.x; b < NBUK; b += 256) {
    int c = hist[b];
    if (c) atomicAdd(&gbase[b], c);
  }
}

// ---------------- pass B: exclusive scan -> boff; cursor = boff ----------------
__global__ void scanB_k(const int* __restrict__ gbase, int* __restrict__ boff,
                        int* __restrict__ cursor) {
  __shared__ int s[256];
  int v = (threadIdx.x < NBUK) ? gbase[threadIdx.x] : 0;
  s[threadIdx.x] = v;
  __syncthreads();
  for (int o = 1; o < 256; o <<= 1) {
    int t = (threadIdx.x >= o) ? s[threadIdx.x - o] : 0;
    __syncthreads();
    s[threadIdx.x] += t;
    __syncthreads();
  }
  if (threadIdx.x < NBUK) {
    int ex = s[threadIdx.x] - v;
    boff[threadIdx.x] = ex;
    cursor[threadIdx.x] = ex;
  }
  if (threadIdx.x == NBUK - 1) boff[NBUK] = s[threadIdx.x];
}

// ---------------- pass A2: scatter packed edges into bucket regions ----------------
__global__ __launch_bounds__(256) void scatterA_k(const int* __restrict__ src,
                                                  const int* __restrict__ dst,
                                                  int* __restrict__ cursor,
                                                  int* __restrict__ tmp) {
  __shared__ int hist[NBUK];
  for (int i = threadIdx.x; i < NBUK; i += 256) hist[i] = 0;
  __syncthreads();
  const int cs = blockIdx.x * BINCHUNK;
  int ce = cs + BINCHUNK;
  if (ce > N_EDGES) ce = N_EDGES;
  for (int e = cs + threadIdx.x; e < ce; e += 256)
    atomicAdd(&hist[dst[e] >> 9], 1);
  __syncthreads();
  for (int b = threadIdx.x; b < NBUK; b += 256) {
    int c = hist[b];
    hist[b] = c ? atomicAdd(&cursor[b], c) : 0;
  }
  __syncthreads();
  for (int e = cs + threadIdx.x; e < ce; e += 256) {
    int d = dst[e];
    int slot = atomicAdd(&hist[d >> 9], 1);
    tmp[slot] = (src[e] << 9) | (d & 511);
  }
}

// ---------------- pass C: per-bucket fine CSR (rowptr + col) ----------------
__global__ __launch_bounds__(512) void csrC_k(const int* __restrict__ tmp,
                                              const int* __restrict__ boff,
                                              int* __restrict__ rp,
                                              int* __restrict__ col) {
  __shared__ int lh[512];
  __shared__ int s[512];
  const int b = blockIdx.x;
  const int tid = threadIdx.x;
  const int eb = boff[b], ee = boff[b + 1];
  lh[tid] = 0;
  __syncthreads();
  for (int e = eb + tid; e < ee; e += 512) atomicAdd(&lh[tmp[e] & 511], 1);
  __syncthreads();
  int v = lh[tid];
  s[tid] = v;
  __syncthreads();
  for (int o = 1; o < 512; o <<= 1) {
    int t = (tid >= o) ? s[tid - o] : 0;
    __syncthreads();
    s[tid] += t;
    __syncthreads();
  }
  const int base = eb + s[tid] - v;
  const int node = b * 512 + tid;
  if (node < N_NODES) rp[node] = base;
  if (b == 0 && tid == 0) rp[N_NODES] = N_EDGES;
  lh[tid] = base;
  __syncthreads();
  for (int e = eb + tid; e < ee; e += 512) {
    int p = tmp[e];
    int slot = atomicAdd(&lh[p & 511], 1);
    col[slot] = p >> 9;
  }
}

// ---------------- MFMA dual transform: outl(bf16) = in@Wl^T, outr(f32) = in@Wr^T ----
// One wave per 16-node strip. A = in[16x64] (bf16), B[k][j] = W[j][k].
// 8 col-tiles (4 Wl + 4 Wr) x 2 K-halves = 16 mfma_f32_16x16x32_bf16.
// A-row / B-col bound to lane&15; k-grouping consistent A/B (permutation-safe).
// C/D mapping: col=lane&15, row=(lane>>4)*4+reg  [m89-verified].
// In-place safe (outr may alias in): wave reads its full strip before storing.
__global__ __launch_bounds__(256) void transform_mfma_k(
    const float* in, const float* __restrict__ Wl, const float* __restrict__ Wr,
    ushort_t* __restrict__ outl, float* outr) {
  const int wid = blockIdx.x * 4 + (threadIdx.x >> 6);
  if (wid >= NSTRIP) return;
  const int lane = threadIdx.x & 63;
  const int row = lane & 15;
  const int kb = lane >> 4;  // k-block 0..3 (8 contiguous k each)

  // B fragments: tile t<4 -> Wl cols, t>=4 -> Wr cols
  bf16x8 Bfrag[8][2];
#pragma unroll
  for (int t = 0; t < 8; ++t) {
    const float* W = (t < 4) ? Wl : Wr;
    const int j = (t & 3) * 16 + row;  // output channel = W row
#pragma unroll
    for (int h = 0; h < 2; ++h) {
      const float* p = W + j * CH + h * 32 + kb * 8;
      float4 w0 = *(const float4*)p;
      float4 w1 = *(const float4*)(p + 4);
      bf16x8 b;
      b[0] = (short)f2bf(w0.x); b[1] = (short)f2bf(w0.y);
      b[2] = (short)f2bf(w0.z); b[3] = (short)f2bf(w0.w);
      b[4] = (short)f2bf(w1.x); b[5] = (short)f2bf(w1.y);
      b[6] = (short)f2bf(w1.z); b[7] = (short)f2bf(w1.w);
      Bfrag[t][h] = b;
    }
  }

  // A fragments for this 16-node strip
  const int n0 = wid * 16;
  bf16x8 Afrag[2];
#pragma unroll
  for (int h = 0; h < 2; ++h) {
    const float* p = in + (size_t)(n0 + row) * CH + h * 32 + kb * 8;
    float4 a0 = *(const float4*)p;
    float4 a1 = *(const float4*)(p + 4);
    bf16x8 a;
    a[0] = (short)f2bf(a0.x); a[1] = (short)f2bf(a0.y);
    a[2] = (short)f2bf(a0.z); a[3] = (short)f2bf(a0.w);
    a[4] = (short)f2bf(a1.x); a[5] = (short)f2bf(a1.y);
    a[6] = (short)f2bf(a1.z); a[7] = (short)f2bf(a1.w);
    Afrag[h] = a;
  }

  f32x4 acc[8];
#pragma unroll
  for (int t = 0; t < 8; ++t) {
    acc[t] = (f32x4){0.f, 0.f, 0.f, 0.f};
    acc[t] = __builtin_amdgcn_mfma_f32_16x16x32_bf16(Afrag[0], Bfrag[t][0],
                                                     acc[t], 0, 0, 0);
    acc[t] = __builtin_amdgcn_mfma_f32_16x16x32_bf16(Afrag[1], Bfrag[t][1],
                                                     acc[t], 0, 0, 0);
  }

  const int orow = (lane >> 4) * 4;
#pragma unroll
  for (int t = 0; t < 4; ++t)
#pragma unroll
    for (int i = 0; i < 4; ++i)
      outl[(size_t)(n0 + orow + i) * CH + t * 16 + row] = f2bf(acc[t][i]);
#pragma unroll
  for (int t = 4; t < 8; ++t)
#pragma unroll
    for (int i = 0; i < 4; ++i)
      outr[(size_t)(n0 + orow + i) * CH + (t - 4) * 16 + row] = acc[t][i];
}

// ---------------- gather(bf16) + mean + bias + relu (+ optional pool) ----------------
template <int MODE>
__global__ __launch_bounds__(256) void gather_k(
    const ushort_t* __restrict__ gl, const float* gr, const float* __restrict__ bl,
    const int* __restrict__ rowptr, const int* __restrict__ col,
    float* outh, const int* __restrict__ batch,
    float* __restrict__ gsum, int* __restrict__ gcnt) {
  const int lane = threadIdx.x & 63;
  const float biasv = bl[lane];
  const int wid = blockIdx.x * (blockDim.x >> 6) + (threadIdx.x >> 6);
  const int nw = gridDim.x * (blockDim.x >> 6);
  const int per = (N_NODES + nw - 1) / nw;
  int ns = wid * per;
  int ne = ns + per;
  if (ne > N_NODES) ne = N_NODES;
  if (ns >= ne) return;

  int curg = -1;
  float paccv = 0.f;
  int pcnt = 0;

  for (int n = ns; n < ne; ++n) {
    const int eb = rowptr[n], ee = rowptr[n + 1];
    float a0 = 0.f, a1 = 0.f, a2 = 0.f, a3 = 0.f;
    float a4 = 0.f, a5 = 0.f, a6 = 0.f, a7 = 0.f;
    int i = eb;
    for (; i + 8 <= ee; i += 8) {
      int c0 = col[i],     c1 = col[i + 1], c2 = col[i + 2], c3 = col[i + 3];
      int c4 = col[i + 4], c5 = col[i + 5], c6 = col[i + 6], c7 = col[i + 7];
      a0 += bf2f(gl[(size_t)c0 * CH + lane]);
      a1 += bf2f(gl[(size_t)c1 * CH + lane]);
      a2 += bf2f(gl[(size_t)c2 * CH + lane]);
      a3 += bf2f(gl[(size_t)c3 * CH + lane]);
      a4 += bf2f(gl[(size_t)c4 * CH + lane]);
      a5 += bf2f(gl[(size_t)c5 * CH + lane]);
      a6 += bf2f(gl[(size_t)c6 * CH + lane]);
      a7 += bf2f(gl[(size_t)c7 * CH + lane]);
    }
    for (; i + 4 <= ee; i += 4) {
      int c0 = col[i], c1 = col[i + 1], c2 = col[i + 2], c3 = col[i + 3];
      a0 += bf2f(gl[(size_t)c0 * CH + lane]);
      a1 += bf2f(gl[(size_t)c1 * CH + lane]);
      a2 += bf2f(gl[(size_t)c2 * CH + lane]);
      a3 += bf2f(gl[(size_t)c3 * CH + lane]);
    }
    for (; i < ee; ++i) a0 += bf2f(gl[(size_t)col[i] * CH + lane]);
    const int deg = ee - eb;
    const float inv = deg > 0 ? 1.f / (float)deg : 1.f;
    const float s = ((a0 + a1) + (a2 + a3)) + ((a4 + a5) + (a6 + a7));
    const float r =
        fmaxf(fmaf(s, inv, biasv + gr[(size_t)n * CH + lane]), 0.f);
    if (MODE == 0) {
      outh[(size_t)n * CH + lane] = r;
    } else {
      int g = batch[n];
      if (g != curg) {
        if (curg >= 0) {
          atomicAdd(&gsum[curg * CH + lane], paccv);
          if (lane == 0) atomicAdd(&gcnt[curg], pcnt);
        }
        curg = g;
        paccv = 0.f;
        pcnt = 0;
      }
      paccv += r;
      pcnt++;
    }
  }
  if (MODE == 1 && curg >= 0) {
    atomicAdd(&gsum[curg * CH + lane], paccv);
    if (lane == 0) atomicAdd(&gcnt[curg], pcnt);
  }
}

// ---------------- final projection ----------------
__global__ void final_k(const float* __restrict__ gsum, const int* __restrict__ gcnt,
                        const float* __restrict__ Wc, const float* __restrict__ bc,
                        float* __restrict__ out) {
  __shared__ float Wcs[OC * CH];
  __shared__ float bcs[OC];
  for (int i = threadIdx.x; i < OC * CH; i += blockDim.x) Wcs[i] = Wc[i];
  if (threadIdx.x < OC) bcs[threadIdx.x] = bc[threadIdx.x];
  __syncthreads();
  int g = threadIdx.x;
  float c = (float)gcnt[g];
  float inv = c > 0.f ? 1.f / c : 1.f;
  float gr[CH];
#pragma unroll
  for (int k = 0; k < CH; ++k) gr[k] = gsum[g * CH + k] * inv;
#pragma unroll
  for (int o = 0; o < OC; ++o) {
    float acc = bcs[o];
#pragma unroll
    for (int k = 0; k < CH; ++k) acc += gr[k] * Wcs[o * CH + k];
    out[g * OC + o] = acc;
  }
}

extern "C" void kernel_launch(void* const* d_in, const int* in_sizes, int n_in,
                              void* d_out, int out_size, void* d_ws, size_t ws_size,
                              hipStream_t stream) {
  const float* x   = (const float*)d_in[0];
  const int*   ei  = (const int*)d_in[1];
  const int*   bat = (const int*)d_in[2];
  const float* W1l = (const float*)d_in[3];
  const float* b1l = (const float*)d_in[4];
  const float* W1r = (const float*)d_in[5];
  const float* W2l = (const float*)d_in[6];
  const float* b2l = (const float*)d_in[7];
  const float* W2r = (const float*)d_in[8];
  const float* Wc  = (const float*)d_in[9];
  const float* bc  = (const float*)d_in[10];
  float* out = (float*)d_out;

  char* ws = (char*)d_ws;
  // buf1: tmp (CSR build) -> xl/h2l as bf16 (12.8 MB)
  // buf2: xr -> h1 -> h2r (f32, row-wise in-place)
  ushort_t* buf1 = (ushort_t*)(ws + 0);         // 12,800,000 B (bf16)
  float* buf2    = (float*)(ws + 25600000);     // 25,600,000 B
  int*   tmp     = (int*)(ws + 0);              //  4,800,000 B (aliased w/ buf1)
  int*   rp      = (int*)(ws + 51200000);       //    400,128 B (incl pad)
  int*   col     = (int*)(ws + 51600128);       //  4,800,000 B
  int*   gbase   = (int*)(ws + 56400128);       //      1,024 B
  int*   boff    = (int*)(ws + 56401152);       //      1,024 B
  int*   cursor  = (int*)(ws + 56402176);       //      1,024 B
  float* gsum    = (float*)(ws + 56403200);     //     65,536 B
  int*   gcnt    = (int*)(ws + 56468736);       //      1,024 B

  const int* src = ei;
  const int* dst = ei + N_EDGES;

  hipMemsetAsync(gbase, 0, NBUK * sizeof(int), stream);
  hipMemsetAsync(gsum, 0, (size_t)NG * CH * sizeof(float) + NG * sizeof(int), stream);

  // ---- CSR build (bucketed counting sort) ----
  countA_k<<<NBLKA, 256, 0, stream>>>(dst, gbase);
  scanB_k<<<1, 256, 0, stream>>>(gbase, boff, cursor);
  scatterA_k<<<NBLKA, 256, 0, stream>>>(src, dst, cursor, tmp);
  csrC_k<<<NBUK, 512, 0, stream>>>(tmp, boff, rp, col);

  // ---- layer 1 ----
  transform_mfma_k<<<(NSTRIP + 3) / 4, 256, 0, stream>>>(x, W1l, W1r, buf1, buf2);
  gather_k<0><<<2048, 256, 0, stream>>>(buf1, buf2, b1l, rp, col, buf2,
                                        nullptr, nullptr, nullptr);     // h1 (f32)
  // ---- layer 2 ----
  transform_mfma_k<<<(NSTRIP + 3) / 4, 256, 0, stream>>>(buf2, W2l, W2r, buf1, buf2);
  gather_k<1><<<2048, 256, 0, stream>>>(buf1, buf2, b2l, rp, col, nullptr,
                                        bat, gsum, gcnt);               // pool
  // ---- classify ----
  final_k<<<1, 256, 0, stream>>>(gsum, gcnt, Wc, bc, out);
}